// Round 12
// baseline (176.618 us; speedup 1.0000x reference)
//
#include <hip/hip_runtime.h>
#include <hip/hip_bf16.h>
#include <stdint.h>

// Problem constants: B=2, H=16, S=2048, D=64, fp32 in/out.
#define BB 2
#define HH 16
#define SS 2048
#define DD 64
constexpr int BH = BB * HH;
constexpr int NT = SS / 64;    // 32 K-tiles
constexpr int QB17 = 32;       // q-tiles of 64 => 32 blocks per bh (fattn17)
constexpr int QB = 16;         // q-tiles of 128 (fallback fattn6)

typedef _Float16 f16_t;
typedef f16_t f16x8 __attribute__((ext_vector_type(8)));
typedef float f32x4 __attribute__((ext_vector_type(4)));

__device__ __forceinline__ uint32_t pkf16(float a, float b) {
    // two fp32 -> packed f16x2 (v_cvt_pkrtz_f16_f32), as raw dword
    return __builtin_bit_cast(uint32_t, __builtin_amdgcn_cvt_pkrtz(a, b));
}
__device__ __forceinline__ float fmax3(float a, float b, float c) {
    return fmaxf(fmaxf(a, b), c);   // fuses to v_max3_f32
}

// =====================================================================
// Pre-pass: pack K -> f16 tiles [64 key][64 d], and V^T·mask -> f16 tiles
// [64 d][64 key], per (bh, kt).  Each row's eight 16B chunks are XOR-
// swizzled (chunk j -> j ^ (row&7)) IN GLOBAL MEMORY so the main kernel's
// linear global_load_lds image is already bank-conflict-free for the
// ds_read_b128 fragment reads.
// =====================================================================
__global__ __launch_bounds__(256)
void prepack(const float* __restrict__ Kg, const float* __restrict__ Vg,
             const float* __restrict__ Mg, f16_t* __restrict__ Kp,
             f16_t* __restrict__ Vp)
{
    __shared__ float Vs[64][65];          // fp32 V tile staging (+1 pad)
    const int bh = blockIdx.x % BH;
    const int kt = blockIdx.x / BH;
    const int b  = bh / HH;
    const int t  = threadIdx.x;
    const size_t gbase = (size_t)bh * SS * DD + (size_t)kt * 64 * DD;
    const size_t tbase = ((size_t)bh * NT + kt) * 4096;   // f16 elements

    // ---- K: 512 chunks of 16B (8 f16) ----
    for (int c = t; c < 512; c += 256) {
        const int row = c >> 3, j = c & 7;
        const float* kp = Kg + gbase + (size_t)row * DD + j * 8;
        float4 a = *(const float4*)kp;
        float4 d = *(const float4*)(kp + 4);
        uint4 w = make_uint4(pkf16(a.x, a.y), pkf16(a.z, a.w),
                             pkf16(d.x, d.y), pkf16(d.z, d.w));
        *(uint4*)&Kp[tbase + (size_t)row * 64 + ((j ^ (row & 7)) * 8)] = w;
    }

    // ---- V: coalesced fp32 load, mask fold, into LDS [key][d] ----
    for (int c = t; c < 1024; c += 256) {
        const int key = c >> 4, dc = (c & 15) * 4;
        float4 v = *(const float4*)(Vg + gbase + (size_t)key * DD + dc);
        const float m = Mg[(size_t)b * SS + kt * 64 + key];
        Vs[key][dc + 0] = v.x * m;
        Vs[key][dc + 1] = v.y * m;
        Vs[key][dc + 2] = v.z * m;
        Vs[key][dc + 3] = v.w * m;
    }
    __syncthreads();

    // ---- V^T: 512 chunks of 16B, transposed out of LDS ----
    for (int c = t; c < 512; c += 256) {
        const int dr = c >> 3, j = c & 7;
        float v0 = Vs[j * 8 + 0][dr], v1 = Vs[j * 8 + 1][dr];
        float v2 = Vs[j * 8 + 2][dr], v3 = Vs[j * 8 + 3][dr];
        float v4 = Vs[j * 8 + 4][dr], v5 = Vs[j * 8 + 5][dr];
        float v6 = Vs[j * 8 + 6][dr], v7 = Vs[j * 8 + 7][dr];
        uint4 w = make_uint4(pkf16(v0, v1), pkf16(v2, v3),
                             pkf16(v4, v5), pkf16(v6, v7));
        *(uint4*)&Vp[tbase + (size_t)dr * 64 + ((j ^ (dr & 7)) * 8)] = w;
    }
}

// =====================================================================
// Main kernel v17 = v16 with the Pt layout FIXED.
// v16's bug: both q-groups' P^T (64 cols each) crammed into one 68-col
// row at offsets 0 and 34 -> overlap + row overflow -> absmax 5.09.
// v17: separate per-group slabs Pt[wave][group][16][68] -- v14's proven
// conflict-free stride-68 pattern, no overlap, aligned 16B reads.
// Geometry: fat waves + max block independence.  64-q blocks = 2 fat
// waves x 128 thr; grid 1024.  LDS 41472 B -> 3 blocks/CU (6 fat
// waves/CU, 3 independent blocks overlapping barrier/vmcnt stalls;
// v12's failure mode was 2).  Each wave: two 16-q groups share every
// K/V fragment read (20 b128/phase vs 36 for two thin waves).
// Sync skeleton byte-identical to proven v13: K dbuf + V delayed-dbuf,
// TWO barriers per phase, uniform 8 stage-loads/phase, counted vmcnt(8).
// Softmax per group: ones-MFMA row sum, shuffle-free deferred max
// (THR=8), fmax3 tree.
// =====================================================================
__global__ __launch_bounds__(128, 2)
void fattn17(const float* __restrict__ Qg, const f16_t* __restrict__ Kp,
             const f16_t* __restrict__ Vp, const float* __restrict__ Sg,
             float* __restrict__ Og)
{
    __shared__ __align__(16) f16_t Kt[2][4096];          // 8KB per buffer
    __shared__ __align__(16) f16_t Vt[2][4096];          // 8KB per buffer
    __shared__ __align__(16) f16_t Pt[2][2][16][68];     // [wave][group][q][key+pad]

    const int bh   = blockIdx.x % BH;      // bh-minor => XCD affinity
    const int qt   = blockIdx.x / BH;      // 0..31
    const int b    = bh / HH;
    const int tid  = threadIdx.x;
    const int wave = tid >> 6;             // 0..1
    const int lane = tid & 63;
    const int l16  = lane & 15;
    const int quad = lane >> 4;

    const float sc = Sg[b] * 1.44269504088896340736f;  // scale*log2e into Q
    const size_t base = (size_t)bh * SS * DD;
    const size_t tb0  = (size_t)bh * NT * 4096;        // f16 elems
    const int q0 = qt * 64 + wave * 32;                // 32 q-rows per wave

    // Staging: 128 threads x 16B = 2KB per instruction (1KB per wave);
    // an 8KB tile = 4 instructions.  LDS dest wave-uniform base; global
    // src PER-LANE.  Instr i covers elems [i*1024, i*1024+1024).
    const f16_t* kroot = Kp + tb0 + wave * 512 + lane * 8;
    const f16_t* vroot = Vp + tb0 + wave * 512 + lane * 8;

    auto stageK = [&](int t, int buf) {
#pragma unroll
        for (int i = 0; i < 4; ++i)
            __builtin_amdgcn_global_load_lds(
                (const __attribute__((address_space(1))) void*)(kroot + (size_t)t * 4096 + i * 1024),
                (__attribute__((address_space(3))) void*)&Kt[buf][i * 1024 + wave * 512], 16, 0, 0);
    };
    auto stageV = [&](int t, int buf) {
#pragma unroll
        for (int i = 0; i < 4; ++i)
            __builtin_amdgcn_global_load_lds(
                (const __attribute__((address_space(1))) void*)(vroot + (size_t)t * 4096 + i * 1024),
                (__attribute__((address_space(3))) void*)&Vt[buf][i * 1024 + wave * 512], 16, 0, 0);
    };

    stageK(0, 0);   // prologue prefetch (4 loads)

    // ---- Q fragments (B-operand layout), fp16 of (q * sc), 2 groups ----
    f16x8 qf[2][2];
#pragma unroll
    for (int g = 0; g < 2; ++g) {
        const float* qp = Qg + base + (size_t)(q0 + g * 16 + l16) * DD + quad * 8;
#pragma unroll
        for (int kc = 0; kc < 2; ++kc) {
            float4 a  = *(const float4*)(qp + kc * 32);
            float4 b4 = *(const float4*)(qp + kc * 32 + 4);
            f16x8 f;
            f[0] = (f16_t)(a.x * sc);  f[1] = (f16_t)(a.y * sc);
            f[2] = (f16_t)(a.z * sc);  f[3] = (f16_t)(a.w * sc);
            f[4] = (f16_t)(b4.x * sc); f[5] = (f16_t)(b4.y * sc);
            f[6] = (f16_t)(b4.z * sc); f[7] = (f16_t)(b4.w * sc);
            qf[g][kc] = f;
        }
    }

    f16x8 ones;
#pragma unroll
    for (int i = 0; i < 8; ++i) ones[i] = (f16_t)1.0f;

    f32x4 Ot[2][4];             // O^T per group: D[m=d][n=q=l16]
#pragma unroll
    for (int g = 0; g < 2; ++g)
#pragma unroll
        for (int mt = 0; mt < 4; ++mt) Ot[g][mt] = f32x4{0.f, 0.f, 0.f, 0.f};
    f32x4 Osum[2] = {f32x4{0.f, 0.f, 0.f, 0.f}, f32x4{0.f, 0.f, 0.f, 0.f}};
    float m_run[2] = {-1e30f, -1e30f};

    const int swz = (l16 & 7) << 3;   // f16-index XOR within a 64-elem row

    // One phase = one 64-key tile t.  Buffer indices passed as literals.
    auto phase = [&](int t, int ksb, int vsb, int krb, int vrb, bool doPV) {
        const int tk = (t + 1 < NT) ? (t + 1) : (NT - 1);   // dummy at end
        stageK(tk, ksb);
        stageV(t, vsb);
        asm volatile("s_waitcnt vmcnt(8)" ::: "memory");    // phase t-1's 8 loads done
        __builtin_amdgcn_s_barrier();   // tile t visible to both waves

        __builtin_amdgcn_s_setprio(1);
        // ---- S^T = K Q^T (tile t); kh shared by both q-groups ----
        f32x4 Sfr[2][4];
#pragma unroll
        for (int mt = 0; mt < 4; ++mt) {
            f32x4 a0 = f32x4{0.f, 0.f, 0.f, 0.f};
            f32x4 a1 = f32x4{0.f, 0.f, 0.f, 0.f};
#pragma unroll
            for (int kc = 0; kc < 2; ++kc) {
                const int off = (mt * 16 + l16) * 64 + ((kc * 32 + quad * 8) ^ swz);
                f16x8 kh = *(const f16x8*)&Kt[krb][off];
                a0 = __builtin_amdgcn_mfma_f32_16x16x32_f16(kh, qf[0][kc], a0, 0, 0, 0);
                a1 = __builtin_amdgcn_mfma_f32_16x16x32_f16(kh, qf[1][kc], a1, 0, 0, 0);
            }
            Sfr[0][mt] = a0;   // D[m=key][n=q=l16], pre-scaled (sc in Q)
            Sfr[1][mt] = a1;
        }

        // ---- O^T += V^T(t-1) P^T(t-1); Osum += 1·P^T(t-1); vf shared ----
        // pf for BOTH groups read here (before softmax overwrites Pt;
        // in-wave DS ordering makes read-then-write safe).
        if (doPV) {
#pragma unroll
            for (int kc = 0; kc < 2; ++kc) {
                f16x8 pf0 = *(const f16x8*)&Pt[wave][0][l16][kc * 32 + quad * 8];
                f16x8 pf1 = *(const f16x8*)&Pt[wave][1][l16][kc * 32 + quad * 8];
#pragma unroll
                for (int mt = 0; mt < 4; ++mt) {
                    const int off = (mt * 16 + l16) * 64 + ((kc * 32 + quad * 8) ^ swz);
                    f16x8 vf = *(const f16x8*)&Vt[vrb][off];
                    Ot[0][mt] = __builtin_amdgcn_mfma_f32_16x16x32_f16(vf, pf0, Ot[0][mt], 0, 0, 0);
                    Ot[1][mt] = __builtin_amdgcn_mfma_f32_16x16x32_f16(vf, pf1, Ot[1][mt], 0, 0, 0);
                }
                Osum[0] = __builtin_amdgcn_mfma_f32_16x16x32_f16(ones, pf0, Osum[0], 0, 0, 0);
                Osum[1] = __builtin_amdgcn_mfma_f32_16x16x32_f16(ones, pf1, Osum[1], 0, 0, 0);
            }
        }
        __builtin_amdgcn_s_setprio(0);

        // ---- Online softmax (tile t), per q-group ----
#pragma unroll
        for (int g = 0; g < 2; ++g) {
            float g0 = fmax3(Sfr[g][0][0], Sfr[g][0][1], Sfr[g][0][2]);
            float g1 = fmax3(Sfr[g][0][3], Sfr[g][1][0], Sfr[g][1][1]);
            float g2 = fmax3(Sfr[g][1][2], Sfr[g][1][3], Sfr[g][2][0]);
            float g3 = fmax3(Sfr[g][2][1], Sfr[g][2][2], Sfr[g][2][3]);
            float g4 = fmax3(Sfr[g][3][0], Sfr[g][3][1], Sfr[g][3][2]);
            float h0 = fmax3(g0, g1, Sfr[g][3][3]);
            float h1 = fmax3(g2, g3, g4);
            const float lmax = fmaxf(h0, h1);   // lane-local (16 keys) max

            // __any over lanes == "some q-column max exceeds m+8".
            if (__any(lmax > m_run[g] + 8.0f)) {
                float mxq = fmaxf(lmax, __shfl_xor(lmax, 16));
                mxq = fmaxf(mxq, __shfl_xor(mxq, 32));     // per-q global max
                const float mnew  = fmaxf(m_run[g], mxq);
                const float alpha = __builtin_amdgcn_exp2f(m_run[g] - mnew);
                m_run[g] = mnew;
#pragma unroll
                for (int mt = 0; mt < 4; ++mt) Ot[g][mt] *= alpha;
                Osum[g] *= alpha;
            }

            float ps[4][4];
#pragma unroll
            for (int mt = 0; mt < 4; ++mt)
#pragma unroll
                for (int r = 0; r < 4; ++r)
                    ps[mt][r] = __builtin_amdgcn_exp2f(Sfr[g][mt][r] - m_run[g]);

            // P^T(t) -> group-g slab (read by PV next phase; same wave)
#pragma unroll
            for (int mt = 0; mt < 4; ++mt) {
                uint2 w = make_uint2(pkf16(ps[mt][0], ps[mt][1]),
                                     pkf16(ps[mt][2], ps[mt][3]));
                *(uint2*)&Pt[wave][g][l16][mt * 16 + quad * 4] = w;
            }
        }

        __builtin_amdgcn_s_barrier();   // reads of K[krb]/V[vrb] done
    };

    // Peeled first pair (phase 0 has no PV), then regular pairs.
    phase(0, /*ks*/1, /*vs*/0, /*kr*/0, /*vr*/1, false);
    phase(1, /*ks*/0, /*vs*/1, /*kr*/1, /*vr*/0, true);
    for (int j = 1; j < NT / 2; ++j) {
        phase(2 * j,     1, 0, 0, 1, true);
        phase(2 * j + 1, 0, 1, 1, 0, true);
    }

    // ---- Drain: PV(NT-1) + Osum(NT-1); V(NT-1) is in Vt[1] ----
    asm volatile("s_waitcnt vmcnt(0)" ::: "memory");
    __builtin_amdgcn_s_barrier();
    {
#pragma unroll
        for (int kc = 0; kc < 2; ++kc) {
            f16x8 pf0 = *(const f16x8*)&Pt[wave][0][l16][kc * 32 + quad * 8];
            f16x8 pf1 = *(const f16x8*)&Pt[wave][1][l16][kc * 32 + quad * 8];
#pragma unroll
            for (int mt = 0; mt < 4; ++mt) {
                const int off = (mt * 16 + l16) * 64 + ((kc * 32 + quad * 8) ^ swz);
                f16x8 vf = *(const f16x8*)&Vt[1][off];
                Ot[0][mt] = __builtin_amdgcn_mfma_f32_16x16x32_f16(vf, pf0, Ot[0][mt], 0, 0, 0);
                Ot[1][mt] = __builtin_amdgcn_mfma_f32_16x16x32_f16(vf, pf1, Ot[1][mt], 0, 0, 0);
            }
            Osum[0] = __builtin_amdgcn_mfma_f32_16x16x32_f16(ones, pf0, Osum[0], 0, 0, 0);
            Osum[1] = __builtin_amdgcn_mfma_f32_16x16x32_f16(ones, pf1, Osum[1], 0, 0, 0);
        }
    }

    // ---- Epilogue: O[q][d] = O^T[d][q] / l   (l = Osum, any row) ----
#pragma unroll
    for (int g = 0; g < 2; ++g) {
        const float inv = 1.0f / Osum[g][0];
        float* op = Og + base + (size_t)(q0 + g * 16 + l16) * DD + quad * 4;
#pragma unroll
        for (int mt = 0; mt < 4; ++mt) {
#pragma unroll
            for (int r = 0; r < 4; ++r)
                op[mt * 16 + r] = Ot[g][mt][r] * inv;
        }
    }
}

// =====================================================================
// Fallback (no/short workspace): previous known-good fused kernel.
// =====================================================================
__global__ __launch_bounds__(512)
void fattn6(const float* __restrict__ Qg, const float* __restrict__ Kg,
            const float* __restrict__ Vg, const float* __restrict__ Mg,
            const float* __restrict__ Sg, float* __restrict__ Og)
{
    __shared__ __align__(16) f16_t Kh_lds[64][72];
    __shared__ __align__(16) f16_t Vt_lds[64][72];
    __shared__ __align__(16) f16_t Pt_lds[8][16][72];
    __shared__ float msk_lds[SS];

    const int bh   = blockIdx.x % BH;
    const int qt   = blockIdx.x / BH;
    const int b    = bh / HH;
    const int tid  = threadIdx.x;
    const int wave = tid >> 6;
    const int lane = tid & 63;
    const int l16  = lane & 15;
    const int quad = lane >> 4;

    const float sc = Sg[b] * 1.44269504088896340736f;
    const size_t base = (size_t)bh * SS * DD;
    const int q0 = qt * 128 + wave * 16;

    for (int i = tid; i < SS; i += 512) msk_lds[i] = Mg[(size_t)b * SS + i];

    f16x8 qf[2];
    {
        const float* qp = Qg + base + (size_t)(q0 + l16) * DD + quad * 8;
#pragma unroll
        for (int kc = 0; kc < 2; ++kc) {
            float4 a  = *(const float4*)(qp + kc * 32);
            float4 b4 = *(const float4*)(qp + kc * 32 + 4);
            f16x8 f;
            f[0] = (f16_t)(a.x * sc);  f[1] = (f16_t)(a.y * sc);
            f[2] = (f16_t)(a.z * sc);  f[3] = (f16_t)(a.w * sc);
            f[4] = (f16_t)(b4.x * sc); f[5] = (f16_t)(b4.y * sc);
            f[6] = (f16_t)(b4.z * sc); f[7] = (f16_t)(b4.w * sc);
            qf[kc] = f;
        }
    }

    f32x4 Ot[4];
#pragma unroll
    for (int mt = 0; mt < 4; ++mt) Ot[mt] = f32x4{0.f, 0.f, 0.f, 0.f};
    float m_run = -1e30f, l_run = 0.0f;

    const int krow = tid >> 3;
    const int kc8  = (tid & 7) * 8;
    const int vd   = tid & 63;
    const int vk0  = (tid >> 6) * 8;

    for (int kt = 0; kt < NT; ++kt) {
        __syncthreads();
        {
            const float* kp = Kg + base + (size_t)(kt * 64 + krow) * DD + kc8;
            float4 a0 = *(const float4*)(kp);
            float4 a1 = *(const float4*)(kp + 4);
            uint4 w = make_uint4(pkf16(a0.x, a0.y), pkf16(a0.z, a0.w),
                                 pkf16(a1.x, a1.y), pkf16(a1.z, a1.w));
            *(uint4*)&Kh_lds[krow][kc8] = w;
        }
        {
            const float* vp = Vg + base + (size_t)(kt * 64 + vk0) * DD + vd;
            const float* mp = &msk_lds[kt * 64 + vk0];
            float v0 = vp[0 * DD] * mp[0], v1 = vp[1 * DD] * mp[1];
            float v2 = vp[2 * DD] * mp[2], v3 = vp[3 * DD] * mp[3];
            float v4 = vp[4 * DD] * mp[4], v5 = vp[5 * DD] * mp[5];
            float v6 = vp[6 * DD] * mp[6], v7 = vp[7 * DD] * mp[7];
            uint4 w = make_uint4(pkf16(v0, v1), pkf16(v2, v3),
                                 pkf16(v4, v5), pkf16(v6, v7));
            *(uint4*)&Vt_lds[vd][vk0] = w;
        }
        __syncthreads();

        f32x4 Sfr[4];
#pragma unroll
        for (int mt = 0; mt < 4; ++mt) {
            f32x4 acc = f32x4{0.f, 0.f, 0.f, 0.f};
#pragma unroll
            for (int kc = 0; kc < 2; ++kc) {
                f16x8 kh = *(const f16x8*)&Kh_lds[mt * 16 + l16][kc * 32 + quad * 8];
                acc = __builtin_amdgcn_mfma_f32_16x16x32_f16(kh, qf[kc], acc, 0, 0, 0);
            }
            Sfr[mt] = acc;
        }

        float mx = Sfr[0][0];
#pragma unroll
        for (int mt = 0; mt < 4; ++mt)
#pragma unroll
            for (int r = 0; r < 4; ++r) mx = fmaxf(mx, Sfr[mt][r]);
        mx = fmaxf(mx, __shfl_xor(mx, 16));
        mx = fmaxf(mx, __shfl_xor(mx, 32));

        if (__any(mx > m_run)) {
            const float mnew  = fmaxf(m_run, mx);
            const float alpha = exp2f(m_run - mnew);
            m_run = mnew;
            l_run *= alpha;
#pragma unroll
            for (int mt = 0; mt < 4; ++mt) Ot[mt] *= alpha;
        }

        float ps[4][4];
        float rs = 0.0f;
#pragma unroll
        for (int mt = 0; mt < 4; ++mt)
#pragma unroll
            for (int r = 0; r < 4; ++r) {
                ps[mt][r] = exp2f(Sfr[mt][r] - m_run);
                rs += ps[mt][r];
            }
        rs += __shfl_xor(rs, 16);
        rs += __shfl_xor(rs, 32);
        l_run += rs;

#pragma unroll
        for (int mt = 0; mt < 4; ++mt) {
            uint2 w = make_uint2(pkf16(ps[mt][0], ps[mt][1]),
                                 pkf16(ps[mt][2], ps[mt][3]));
            *(uint2*)&Pt_lds[wave][l16][mt * 16 + quad * 4] = w;
        }

#pragma unroll
        for (int kc = 0; kc < 2; ++kc) {
            f16x8 pf = *(const f16x8*)&Pt_lds[wave][l16][kc * 32 + quad * 8];
#pragma unroll
            for (int mt = 0; mt < 4; ++mt) {
                f16x8 vf = *(const f16x8*)&Vt_lds[mt * 16 + l16][kc * 32 + quad * 8];
                Ot[mt] = __builtin_amdgcn_mfma_f32_16x16x32_f16(vf, pf, Ot[mt], 0, 0, 0);
            }
        }
    }

    const float inv = 1.0f / l_run;
    float* op = Og + base + (size_t)(q0 + l16) * DD + quad * 4;
#pragma unroll
    for (int mt = 0; mt < 4; ++mt) {
#pragma unroll
        for (int r = 0; r < 4; ++r)
            op[mt * 16 + r] = Ot[mt][r] * inv;
    }
}

extern "C" void kernel_launch(void* const* d_in, const int* in_sizes, int n_in,
                              void* d_out, int out_size, void* d_ws, size_t ws_size,
                              hipStream_t stream) {
    const float* Qg = (const float*)d_in[0];
    const float* Kg = (const float*)d_in[1];
    const float* Vg = (const float*)d_in[2];
    // d_in[3] = query_mask (all ones, unused by reference)
    const float* Mg = (const float*)d_in[4];  // key_mask [B,1,1,S]
    const float* Sg = (const float*)d_in[5];  // scale_factor [B,1,1,1]
    // d_in[6] = dropout (0, identity)
    float* Og = (float*)d_out;

    const size_t kv_elems = (size_t)BH * SS * DD;          // per array, f16
    const size_t need = 2 * kv_elems * sizeof(f16_t);      // 16.8 MB

    if (d_ws != nullptr && ws_size >= need) {
        f16_t* Kp = (f16_t*)d_ws;
        f16_t* Vp = Kp + kv_elems;
        prepack<<<dim3(BH * NT), dim3(256), 0, stream>>>(Kg, Vg, Mg, Kp, Vp);
        fattn17<<<dim3(BH * QB17), dim3(128), 0, stream>>>(Qg, Kp, Vp, Sg, Og);
    } else {
        fattn6<<<dim3(BH * QB), dim3(512), 0, stream>>>(Qg, Kg, Vg, Mg, Sg, Og);
    }
}

// Round 13
// 145.158 us; speedup vs baseline: 1.2167x; 1.2167x over previous
//
#include <hip/hip_runtime.h>
#include <hip/hip_bf16.h>
#include <stdint.h>

// Problem constants: B=2, H=16, S=2048, D=64, fp32 in/out.
#define BB 2
#define HH 16
#define SS 2048
#define DD 64
constexpr int BH = BB * HH;
constexpr int NT = SS / 64;    // 32 K-tiles
constexpr int QB = 16;         // q-tiles of 128 => 16 blocks per bh

typedef _Float16 f16_t;
typedef f16_t f16x8 __attribute__((ext_vector_type(8)));
typedef float f32x4 __attribute__((ext_vector_type(4)));

__device__ __forceinline__ uint32_t pkf16(float a, float b) {
    // two fp32 -> packed f16x2 (v_cvt_pkrtz_f16_f32), as raw dword
    return __builtin_bit_cast(uint32_t, __builtin_amdgcn_cvt_pkrtz(a, b));
}
__device__ __forceinline__ float fmax3(float a, float b, float c) {
    return fmaxf(fmaxf(a, b), c);   // fuses to v_max3_f32
}

// =====================================================================
// Pre-pass: pack K -> f16 tiles [64 key][64 d], and V^T·mask -> f16 tiles
// [64 d][64 key], per (bh, kt).  Each row's eight 16B chunks are XOR-
// swizzled (chunk j -> j ^ (row&7)) IN GLOBAL MEMORY so the main kernel's
// linear global_load_lds image is already bank-conflict-free for the
// ds_read_b128 fragment reads.
// =====================================================================
__global__ __launch_bounds__(256)
void prepack(const float* __restrict__ Kg, const float* __restrict__ Vg,
             const float* __restrict__ Mg, f16_t* __restrict__ Kp,
             f16_t* __restrict__ Vp)
{
    __shared__ float Vs[64][65];          // fp32 V tile staging (+1 pad)
    const int bh = blockIdx.x % BH;
    const int kt = blockIdx.x / BH;
    const int b  = bh / HH;
    const int t  = threadIdx.x;
    const size_t gbase = (size_t)bh * SS * DD + (size_t)kt * 64 * DD;
    const size_t tbase = ((size_t)bh * NT + kt) * 4096;   // f16 elements

    // ---- K: 512 chunks of 16B (8 f16) ----
    for (int c = t; c < 512; c += 256) {
        const int row = c >> 3, j = c & 7;
        const float* kp = Kg + gbase + (size_t)row * DD + j * 8;
        float4 a = *(const float4*)kp;
        float4 d = *(const float4*)(kp + 4);
        uint4 w = make_uint4(pkf16(a.x, a.y), pkf16(a.z, a.w),
                             pkf16(d.x, d.y), pkf16(d.z, d.w));
        *(uint4*)&Kp[tbase + (size_t)row * 64 + ((j ^ (row & 7)) * 8)] = w;
    }

    // ---- V: coalesced fp32 load, mask fold, into LDS [key][d] ----
    for (int c = t; c < 1024; c += 256) {
        const int key = c >> 4, dc = (c & 15) * 4;
        float4 v = *(const float4*)(Vg + gbase + (size_t)key * DD + dc);
        const float m = Mg[(size_t)b * SS + kt * 64 + key];
        Vs[key][dc + 0] = v.x * m;
        Vs[key][dc + 1] = v.y * m;
        Vs[key][dc + 2] = v.z * m;
        Vs[key][dc + 3] = v.w * m;
    }
    __syncthreads();

    // ---- V^T: 512 chunks of 16B, transposed out of LDS ----
    for (int c = t; c < 512; c += 256) {
        const int dr = c >> 3, j = c & 7;
        float v0 = Vs[j * 8 + 0][dr], v1 = Vs[j * 8 + 1][dr];
        float v2 = Vs[j * 8 + 2][dr], v3 = Vs[j * 8 + 3][dr];
        float v4 = Vs[j * 8 + 4][dr], v5 = Vs[j * 8 + 5][dr];
        float v6 = Vs[j * 8 + 6][dr], v7 = Vs[j * 8 + 7][dr];
        uint4 w = make_uint4(pkf16(v0, v1), pkf16(v2, v3),
                             pkf16(v4, v5), pkf16(v6, v7));
        *(uint4*)&Vp[tbase + (size_t)dr * 64 + ((j ^ (dr & 7)) * 8)] = w;
    }
}

// =====================================================================
// Main kernel v13 (the measured champion: 60.2-62.3 us, total 145.6):
// fattn10's proven geometry (512 thr, 8 waves, 16 q/wave; 16 waves/CU --
// the TLP that the fat-wave arc, R6/R10/R12, proved is load-bearing):
//  1. V DOUBLE-buffer via DELAYED staging: phase t stages K(t+1) and V(t)
//     (V(t) is only read at phase t+1, so 2-deep suffices).  Hazards:
//     overwritten buffers were last read in the phase sealed by the
//     immediately-preceding bottom barrier; readers covered by per-wave
//     vmcnt(2) + top barrier (identical discipline to fattn10).
//  2. 2-phase unroll: even/odd phases have literal buffer indices ->
//     ds_read bases are compile-time, vcur/kcur rotation VALU gone.
//  3. Branch-free staging: always exactly 2 loads/phase (final K issue
//     clamped to a dummy reload of tile 31 into the dead buffer) ->
//     uniform vmcnt(2); drain does vmcnt(0).
// Softmax/PV: S(t) then PV(t-1) (pipe overlap), ones-MFMA row sum,
// shuffle-free deferred max (THR=8), fmax3 tree, raw v_exp_f32.
// =====================================================================
__global__ __launch_bounds__(512)
void fattn13(const float* __restrict__ Qg, const f16_t* __restrict__ Kp,
             const f16_t* __restrict__ Vp, const float* __restrict__ Sg,
             float* __restrict__ Og)
{
    __shared__ __align__(16) f16_t Kt[2][4096];          // 8KB per buffer
    __shared__ __align__(16) f16_t Vt[2][4096];          // 8KB per buffer
    __shared__ __align__(16) f16_t Pt[8][16][72];        // per-wave P^T

    const int bh   = blockIdx.x % BH;      // bh-minor => XCD affinity
    const int qt   = blockIdx.x / BH;
    const int b    = bh / HH;
    const int tid  = threadIdx.x;
    const int wave = tid >> 6;
    const int lane = tid & 63;
    const int l16  = lane & 15;
    const int quad = lane >> 4;

    const float sc = Sg[b] * 1.44269504088896340736f;  // scale*log2e into Q
    const size_t base = (size_t)bh * SS * DD;
    const size_t tb0  = (size_t)bh * NT * 4096;        // f16 elems
    const int q0 = qt * 128 + wave * 16;

    // Per-lane global staging roots (16B chunk per thread per array).
    const f16_t* kroot = Kp + tb0 + tid * 8;
    const f16_t* vroot = Vp + tb0 + tid * 8;

    auto stageK = [&](int t, int buf) {
        __builtin_amdgcn_global_load_lds(
            (const __attribute__((address_space(1))) void*)(kroot + (size_t)t * 4096),
            (__attribute__((address_space(3))) void*)&Kt[buf][wave * 512], 16, 0, 0);
    };
    auto stageV = [&](int t, int buf) {
        __builtin_amdgcn_global_load_lds(
            (const __attribute__((address_space(1))) void*)(vroot + (size_t)t * 4096),
            (__attribute__((address_space(3))) void*)&Vt[buf][wave * 512], 16, 0, 0);
    };

    stageK(0, 0);   // prologue prefetch

    // ---- Q fragments (B-operand layout), fp16 of (q * sc) ----
    f16x8 qf[2];
    {
        const float* qp = Qg + base + (size_t)(q0 + l16) * DD + quad * 8;
#pragma unroll
        for (int kc = 0; kc < 2; ++kc) {
            float4 a  = *(const float4*)(qp + kc * 32);
            float4 b4 = *(const float4*)(qp + kc * 32 + 4);
            f16x8 f;
            f[0] = (f16_t)(a.x * sc);  f[1] = (f16_t)(a.y * sc);
            f[2] = (f16_t)(a.z * sc);  f[3] = (f16_t)(a.w * sc);
            f[4] = (f16_t)(b4.x * sc); f[5] = (f16_t)(b4.y * sc);
            f[6] = (f16_t)(b4.z * sc); f[7] = (f16_t)(b4.w * sc);
            qf[kc] = f;
        }
    }

    f16x8 ones;
#pragma unroll
    for (int i = 0; i < 8; ++i) ones[i] = (f16_t)1.0f;

    f32x4 Ot[4];                // O^T: D[m=d=mt*16+quad*4+r][n=q=l16]
#pragma unroll
    for (int mt = 0; mt < 4; ++mt) Ot[mt] = f32x4{0.f, 0.f, 0.f, 0.f};
    f32x4 Osum = f32x4{0.f, 0.f, 0.f, 0.f};   // all rows = sum_k P^T[k][q]
    float m_run = -1e30f;

    const int swz = (l16 & 7) << 3;   // f16-index XOR within a 64-elem row

    // One phase = one 64-key tile t.  ksb/vsb: stage targets, krb/vrb:
    // read sources -- all passed as literals so LDS bases fold.
    auto phase = [&](int t, int ksb, int vsb, int krb, int vrb, bool doPV) {
        const int tk = (t + 1 < NT) ? (t + 1) : (NT - 1);   // dummy at end
        stageK(tk, ksb);
        stageV(t, vsb);
        asm volatile("s_waitcnt vmcnt(2)" ::: "memory");    // phase t-1 loads done
        __builtin_amdgcn_s_barrier();   // tile t visible to all waves

        __builtin_amdgcn_s_setprio(1);
        // ---- S^T = K Q^T  (tile t) ----
        f32x4 Sfr[4];
#pragma unroll
        for (int mt = 0; mt < 4; ++mt) {
            f32x4 acc = f32x4{0.f, 0.f, 0.f, 0.f};
#pragma unroll
            for (int kc = 0; kc < 2; ++kc) {
                const int off = (mt * 16 + l16) * 64 + ((kc * 32 + quad * 8) ^ swz);
                f16x8 kh = *(const f16x8*)&Kt[krb][off];
                acc = __builtin_amdgcn_mfma_f32_16x16x32_f16(kh, qf[kc], acc, 0, 0, 0);
            }
            Sfr[mt] = acc;   // D[m=key][n=q=l16], pre-scaled (sc in Q)
        }

        // ---- O^T += V^T(t-1) P^T(t-1); Osum += 1·P^T(t-1) ----
        if (doPV) {
#pragma unroll
            for (int kc = 0; kc < 2; ++kc) {
                f16x8 pf = *(const f16x8*)&Pt[wave][l16][kc * 32 + quad * 8];
#pragma unroll
                for (int mt = 0; mt < 4; ++mt) {
                    const int off = (mt * 16 + l16) * 64 + ((kc * 32 + quad * 8) ^ swz);
                    f16x8 vf = *(const f16x8*)&Vt[vrb][off];
                    Ot[mt] = __builtin_amdgcn_mfma_f32_16x16x32_f16(vf, pf, Ot[mt], 0, 0, 0);
                }
                Osum = __builtin_amdgcn_mfma_f32_16x16x32_f16(ones, pf, Osum, 0, 0, 0);
            }
        }
        __builtin_amdgcn_s_setprio(0);

        // ---- Online softmax (tile t): 16 in-lane values (q = l16) ----
        float g0 = fmax3(Sfr[0][0], Sfr[0][1], Sfr[0][2]);
        float g1 = fmax3(Sfr[0][3], Sfr[1][0], Sfr[1][1]);
        float g2 = fmax3(Sfr[1][2], Sfr[1][3], Sfr[2][0]);
        float g3 = fmax3(Sfr[2][1], Sfr[2][2], Sfr[2][3]);
        float g4 = fmax3(Sfr[3][0], Sfr[3][1], Sfr[3][2]);
        float h0 = fmax3(g0, g1, Sfr[3][3]);
        float h1 = fmax3(g2, g3, g4);
        const float lmax = fmaxf(h0, h1);   // lane-local (16 keys) max

        // __any over lanes == "some q-column max exceeds m+8" (OR == max).
        if (__any(lmax > m_run + 8.0f)) {
            float mxq = fmaxf(lmax, __shfl_xor(lmax, 16));
            mxq = fmaxf(mxq, __shfl_xor(mxq, 32));     // per-q global max
            const float mnew  = fmaxf(m_run, mxq);
            const float alpha = __builtin_amdgcn_exp2f(m_run - mnew);
            m_run = mnew;
#pragma unroll
            for (int mt = 0; mt < 4; ++mt) Ot[mt] *= alpha;
            Osum *= alpha;
        }

        float ps[4][4];
#pragma unroll
        for (int mt = 0; mt < 4; ++mt)
#pragma unroll
            for (int r = 0; r < 4; ++r)
                ps[mt][r] = __builtin_amdgcn_exp2f(Sfr[mt][r] - m_run);

        // ---- P^T(t) -> LDS (read by PV next phase; same wave) ----
#pragma unroll
        for (int mt = 0; mt < 4; ++mt) {
            uint2 w = make_uint2(pkf16(ps[mt][0], ps[mt][1]),
                                 pkf16(ps[mt][2], ps[mt][3]));
            *(uint2*)&Pt[wave][l16][mt * 16 + quad * 4] = w;
        }

        __builtin_amdgcn_s_barrier();   // reads of K[krb]/V[vrb] done
    };

    // Peeled first pair (phase 0 has no PV), then regular pairs.
    phase(0, /*ks*/1, /*vs*/0, /*kr*/0, /*vr*/1, false);
    phase(1, /*ks*/0, /*vs*/1, /*kr*/1, /*vr*/0, true);
    for (int j = 1; j < NT / 2; ++j) {
        phase(2 * j,     1, 0, 0, 1, true);
        phase(2 * j + 1, 0, 1, 1, 0, true);
    }

    // ---- Drain: PV(NT-1) + Osum(NT-1); V(NT-1) is in Vt[1] ----
    asm volatile("s_waitcnt vmcnt(0)" ::: "memory");
    __builtin_amdgcn_s_barrier();
    {
#pragma unroll
        for (int kc = 0; kc < 2; ++kc) {
            f16x8 pf = *(const f16x8*)&Pt[wave][l16][kc * 32 + quad * 8];
#pragma unroll
            for (int mt = 0; mt < 4; ++mt) {
                const int off = (mt * 16 + l16) * 64 + ((kc * 32 + quad * 8) ^ swz);
                f16x8 vf = *(const f16x8*)&Vt[1][off];
                Ot[mt] = __builtin_amdgcn_mfma_f32_16x16x32_f16(vf, pf, Ot[mt], 0, 0, 0);
            }
            Osum = __builtin_amdgcn_mfma_f32_16x16x32_f16(ones, pf, Osum, 0, 0, 0);
        }
    }

    // ---- Epilogue: O[q][d] = O^T[d][q] / l   (l = Osum, any row) ----
    const float inv = 1.0f / Osum[0];
    float* op = Og + base + (size_t)(q0 + l16) * DD + quad * 4;
#pragma unroll
    for (int mt = 0; mt < 4; ++mt) {
#pragma unroll
        for (int r = 0; r < 4; ++r)
            op[mt * 16 + r] = Ot[mt][r] * inv;
    }
}

// =====================================================================
// Fallback (no/short workspace): previous known-good fused kernel.
// =====================================================================
__global__ __launch_bounds__(512)
void fattn6(const float* __restrict__ Qg, const float* __restrict__ Kg,
            const float* __restrict__ Vg, const float* __restrict__ Mg,
            const float* __restrict__ Sg, float* __restrict__ Og)
{
    __shared__ __align__(16) f16_t Kh_lds[64][72];
    __shared__ __align__(16) f16_t Vt_lds[64][72];
    __shared__ __align__(16) f16_t Pt_lds[8][16][72];
    __shared__ float msk_lds[SS];

    const int bh   = blockIdx.x % BH;
    const int qt   = blockIdx.x / BH;
    const int b    = bh / HH;
    const int tid  = threadIdx.x;
    const int wave = tid >> 6;
    const int lane = tid & 63;
    const int l16  = lane & 15;
    const int quad = lane >> 4;

    const float sc = Sg[b] * 1.44269504088896340736f;
    const size_t base = (size_t)bh * SS * DD;
    const int q0 = qt * 128 + wave * 16;

    for (int i = tid; i < SS; i += 512) msk_lds[i] = Mg[(size_t)b * SS + i];

    f16x8 qf[2];
    {
        const float* qp = Qg + base + (size_t)(q0 + l16) * DD + quad * 8;
#pragma unroll
        for (int kc = 0; kc < 2; ++kc) {
            float4 a  = *(const float4*)(qp + kc * 32);
            float4 b4 = *(const float4*)(qp + kc * 32 + 4);
            f16x8 f;
            f[0] = (f16_t)(a.x * sc);  f[1] = (f16_t)(a.y * sc);
            f[2] = (f16_t)(a.z * sc);  f[3] = (f16_t)(a.w * sc);
            f[4] = (f16_t)(b4.x * sc); f[5] = (f16_t)(b4.y * sc);
            f[6] = (f16_t)(b4.z * sc); f[7] = (f16_t)(b4.w * sc);
            qf[kc] = f;
        }
    }

    f32x4 Ot[4];
#pragma unroll
    for (int mt = 0; mt < 4; ++mt) Ot[mt] = f32x4{0.f, 0.f, 0.f, 0.f};
    float m_run = -1e30f, l_run = 0.0f;

    const int krow = tid >> 3;
    const int kc8  = (tid & 7) * 8;
    const int vd   = tid & 63;
    const int vk0  = (tid >> 6) * 8;

    for (int kt = 0; kt < NT; ++kt) {
        __syncthreads();
        {
            const float* kp = Kg + base + (size_t)(kt * 64 + krow) * DD + kc8;
            float4 a0 = *(const float4*)(kp);
            float4 a1 = *(const float4*)(kp + 4);
            uint4 w = make_uint4(pkf16(a0.x, a0.y), pkf16(a0.z, a0.w),
                                 pkf16(a1.x, a1.y), pkf16(a1.z, a1.w));
            *(uint4*)&Kh_lds[krow][kc8] = w;
        }
        {
            const float* vp = Vg + base + (size_t)(kt * 64 + vk0) * DD + vd;
            const float* mp = &msk_lds[kt * 64 + vk0];
            float v0 = vp[0 * DD] * mp[0], v1 = vp[1 * DD] * mp[1];
            float v2 = vp[2 * DD] * mp[2], v3 = vp[3 * DD] * mp[3];
            float v4 = vp[4 * DD] * mp[4], v5 = vp[5 * DD] * mp[5];
            float v6 = vp[6 * DD] * mp[6], v7 = vp[7 * DD] * mp[7];
            uint4 w = make_uint4(pkf16(v0, v1), pkf16(v2, v3),
                                 pkf16(v4, v5), pkf16(v6, v7));
            *(uint4*)&Vt_lds[vd][vk0] = w;
        }
        __syncthreads();

        f32x4 Sfr[4];
#pragma unroll
        for (int mt = 0; mt < 4; ++mt) {
            f32x4 acc = f32x4{0.f, 0.f, 0.f, 0.f};
#pragma unroll
            for (int kc = 0; kc < 2; ++kc) {
                f16x8 kh = *(const f16x8*)&Kh_lds[mt * 16 + l16][kc * 32 + quad * 8];
                acc = __builtin_amdgcn_mfma_f32_16x16x32_f16(kh, qf[kc], acc, 0, 0, 0);
            }
            Sfr[mt] = acc;
        }

        float mx = Sfr[0][0];
#pragma unroll
        for (int mt = 0; mt < 4; ++mt)
#pragma unroll
            for (int r = 0; r < 4; ++r) mx = fmaxf(mx, Sfr[mt][r]);
        mx = fmaxf(mx, __shfl_xor(mx, 16));
        mx = fmaxf(mx, __shfl_xor(mx, 32));

        if (__any(mx > m_run)) {
            const float mnew  = fmaxf(m_run, mx);
            const float alpha = exp2f(m_run - mnew);
            m_run = mnew;
            l_run *= alpha;
#pragma unroll
            for (int mt = 0; mt < 4; ++mt) Ot[mt] *= alpha;
        }

        float ps[4][4];
        float rs = 0.0f;
#pragma unroll
        for (int mt = 0; mt < 4; ++mt)
#pragma unroll
            for (int r = 0; r < 4; ++r) {
                ps[mt][r] = exp2f(Sfr[mt][r] - m_run);
                rs += ps[mt][r];
            }
        rs += __shfl_xor(rs, 16);
        rs += __shfl_xor(rs, 32);
        l_run += rs;

#pragma unroll
        for (int mt = 0; mt < 4; ++mt) {
            uint2 w = make_uint2(pkf16(ps[mt][0], ps[mt][1]),
                                 pkf16(ps[mt][2], ps[mt][3]));
            *(uint2*)&Pt_lds[wave][l16][mt * 16 + quad * 4] = w;
        }

#pragma unroll
        for (int kc = 0; kc < 2; ++kc) {
            f16x8 pf = *(const f16x8*)&Pt_lds[wave][l16][kc * 32 + quad * 8];
#pragma unroll
            for (int mt = 0; mt < 4; ++mt) {
                f16x8 vf = *(const f16x8*)&Vt_lds[mt * 16 + l16][kc * 32 + quad * 8];
                Ot[mt] = __builtin_amdgcn_mfma_f32_16x16x32_f16(vf, pf, Ot[mt], 0, 0, 0);
            }
        }
    }

    const float inv = 1.0f / l_run;
    float* op = Og + base + (size_t)(q0 + l16) * DD + quad * 4;
#pragma unroll
    for (int mt = 0; mt < 4; ++mt) {
#pragma unroll
        for (int r = 0; r < 4; ++r)
            op[mt * 16 + r] = Ot[mt][r] * inv;
    }
}

extern "C" void kernel_launch(void* const* d_in, const int* in_sizes, int n_in,
                              void* d_out, int out_size, void* d_ws, size_t ws_size,
                              hipStream_t stream) {
    const float* Qg = (const float*)d_in[0];
    const float* Kg = (const float*)d_in[1];
    const float* Vg = (const float*)d_in[2];
    // d_in[3] = query_mask (all ones, unused by reference)
    const float* Mg = (const float*)d_in[4];  // key_mask [B,1,1,S]
    const float* Sg = (const float*)d_in[5];  // scale_factor [B,1,1,1]
    // d_in[6] = dropout (0, identity)
    float* Og = (float*)d_out;

    const size_t kv_elems = (size_t)BH * SS * DD;          // per array, f16
    const size_t need = 2 * kv_elems * sizeof(f16_t);      // 16.8 MB

    if (d_ws != nullptr && ws_size >= need) {
        f16_t* Kp = (f16_t*)d_ws;
        f16_t* Vp = Kp + kv_elems;
        prepack<<<dim3(BH * NT), dim3(256), 0, stream>>>(Kg, Vg, Mg, Kp, Vp);
        fattn13<<<dim3(BH * QB), dim3(512), 0, stream>>>(Qg, Kp, Vp, Sg, Og);
    } else {
        fattn6<<<dim3(BH * QB), dim3(512), 0, stream>>>(Qg, Kg, Vg, Mg, Sg, Og);
    }
}